// Round 3
// baseline (299.644 us; speedup 1.0000x reference)
//
#include <hip/hip_runtime.h>
#include <hip/hip_bf16.h>

// Dense FFN: out = relu(x @ w1 + b1) @ w2 + b2
// x  [8192,1024] f32, w1 [1024,4096] f32, b1 [4096] f32,
// w2 [4096,1024] f32, b2 [1024] f32, out [8192,1024] f32.
//
// R3 (resubmit x2 after broker timeouts): pipelined GEMM (T3+T4+T5+T1).
//   Tile 256x128, BK=64, 512 thr (8 waves, 4Mx2N, 64x64 per wave).
//   3-deep LDS ring (144 KiB): compute tile t from buf[t%3] while staging
//   tile t+2 into buf[(t+2)%3] (= buf of t-1, freed at t-1's final barrier).
//   Counted s_waitcnt vmcnt(6) once per K-tile -- never drains to 0 in the
//   main loop -- so global_load_lds prefetch stays in flight across barriers.
//   2 phases per K-tile, each {ds_read || gload -> barrier -> lgkmcnt(0) ->
//   setprio(1) -> 16 MFMA -> setprio(0) -> barrier}.
//   Chunk-XOR LDS swizzle identical to the verified R2 kernel (0 conflicts).
//   Grid: 1D + XCD-bijective N-major remap (per-XCD L2 panel reuse).

typedef __bf16 bf16;
typedef __bf16 bf16x4 __attribute__((ext_vector_type(4)));
typedef __bf16 bf16x8 __attribute__((ext_vector_type(8)));
typedef float  f32x4  __attribute__((ext_vector_type(4)));

#define BM 256
#define BN 128
#define BK 64

__device__ __forceinline__ void gload_lds16(const bf16* g, bf16* l) {
    __builtin_amdgcn_global_load_lds(
        (const __attribute__((address_space(1))) unsigned int*)g,
        (__attribute__((address_space(3))) unsigned int*)l,
        16, 0, 0);
}

// ---------------------------------------------------------------------------
// cast f32 -> bf16, 4 elems/thread
__global__ __launch_bounds__(256) void cast_f32_bf16(
    const float4* __restrict__ in, bf16x4* __restrict__ out, int n4)
{
    int i = blockIdx.x * 256 + threadIdx.x;
    if (i < n4) {
        float4 v = in[i];
        bf16x4 o;
        o.x = (bf16)v.x; o.y = (bf16)v.y; o.z = (bf16)v.z; o.w = (bf16)v.w;
        out[i] = o;
    }
}

// ---------------------------------------------------------------------------
// transpose + cast: in [K][N] f32  ->  out [N][K] bf16.  64x64 tiles.
__global__ __launch_bounds__(256) void transpose_cast(
    const float* __restrict__ in, bf16* __restrict__ out, int K, int N)
{
    __shared__ __align__(16) bf16 tile[64][72];   // [n][k], pad to 72
    const int k0 = blockIdx.y * 64;
    const int n0 = blockIdx.x * 64;
    const int t  = threadIdx.x;

    const int lr = t >> 4;          // 0..15
    const int lc = (t & 15) << 2;   // 0,4,..60
#pragma unroll
    for (int p = 0; p < 4; ++p) {
        int k = p * 16 + lr;
        float4 v = *(const float4*)(in + (size_t)(k0 + k) * N + n0 + lc);
        tile[lc + 0][k] = (bf16)v.x;
        tile[lc + 1][k] = (bf16)v.y;
        tile[lc + 2][k] = (bf16)v.z;
        tile[lc + 3][k] = (bf16)v.w;
    }
    __syncthreads();

    const int wr = t >> 3;          // 0..31
    const int wc = (t & 7) << 3;    // 0,8,..56
#pragma unroll
    for (int p = 0; p < 2; ++p) {
        int n = p * 32 + wr;
        *(bf16x8*)(out + (size_t)(n0 + n) * K + k0 + wc) =
            *(const bf16x8*)&tile[n][wc];
    }
}

// ---------------------------------------------------------------------------
// C[m][n] = sum_k A[m][k] * Bt[n][k]  (+bias, opt relu)
// A [M][K] bf16, Bt [N][K] bf16.
template <int FUSE_RELU_BF16>
__global__ __launch_bounds__(512, 2) void gemm_bt(
    const bf16* __restrict__ A, const bf16* __restrict__ Bt,
    const float* __restrict__ bias, void* __restrict__ Cout,
    int M, int N, int K, int ny)
{
    // 3-deep ring: A 3x(256x64), B 3x(128x64) bf16 = 144 KiB
    __shared__ __align__(16) bf16 As[3 * BM * BK];
    __shared__ __align__(16) bf16 Bs[3 * BN * BK];

    // XCD-bijective remap, N-major tile order (nwg % 8 == 0 for our shapes)
    const int nwg = gridDim.x;
    const int bid = blockIdx.x;
    const int L   = (bid & 7) * (nwg >> 3) + (bid >> 3);
    const int tx  = L / ny;          // N-block
    const int ty  = L - tx * ny;     // M-block

    const int tid  = threadIdx.x;
    const int wave = tid >> 6;       // 0..7
    const int lane = tid & 63;
    const int l8   = lane >> 3;      // row within 8-row staging group
    const int c8   = lane & 7;       // LDS chunk slot
    const int swc  = (c8 ^ l8) << 3; // swizzled global chunk -> elem offset
    const size_t K_ = (size_t)K;

    // staging: one "round" = 512 thr x 16B = 64 rows x 64 elems.
    // A needs 4 rounds (256 rows), B needs 2 rounds (128 rows): 6 loads/tile.
    const bf16* gA_s[4]; const bf16* gB_s[2];
    int ldsAo[4], ldsBo[2];
#pragma unroll
    for (int j = 0; j < 4; ++j) {
        gA_s[j]  = A + ((size_t)ty * BM + j * 64 + wave * 8 + l8) * K_ + swc;
        ldsAo[j] = (j * 64 + wave * 8) * BK + lane * 8;
    }
#pragma unroll
    for (int j = 0; j < 2; ++j) {
        gB_s[j]  = Bt + ((size_t)tx * BN + j * 64 + wave * 8 + l8) * K_ + swc;
        ldsBo[j] = (j * 64 + wave * 8) * BK + lane * 8;
    }

    const int wm   = (wave >> 1) << 6;   // 0,64,128,192
    const int wn   = (wave & 1) << 6;    // 0,64
    const int quad = lane >> 4;
    const int r    = lane & 15;
    const int r7   = lane & 7;

    const int NT = K >> 6;

    // ---- prologue: stage tiles 0 (buf0) and 1 (buf1) ----
#pragma unroll
    for (int j = 0; j < 4; ++j) gload_lds16(gA_s[j], As + ldsAo[j]);
#pragma unroll
    for (int j = 0; j < 2; ++j) gload_lds16(gB_s[j], Bs + ldsBo[j]);
#pragma unroll
    for (int j = 0; j < 4; ++j) gA_s[j] += BK;
#pragma unroll
    for (int j = 0; j < 2; ++j) gB_s[j] += BK;
#pragma unroll
    for (int j = 0; j < 4; ++j) gload_lds16(gA_s[j], As + BM * BK + ldsAo[j]);
#pragma unroll
    for (int j = 0; j < 2; ++j) gload_lds16(gB_s[j], Bs + BN * BK + ldsBo[j]);
#pragma unroll
    for (int j = 0; j < 4; ++j) gA_s[j] += BK;
#pragma unroll
    for (int j = 0; j < 2; ++j) gB_s[j] += BK;

    asm volatile("s_waitcnt vmcnt(6)" ::: "memory");   // tile 0 landed
    __builtin_amdgcn_s_barrier();
    asm volatile("" ::: "memory");

    f32x4 acc[4][4] = {};
    int bc = 0;   // compute buffer = t % 3

    for (int t = 0; t < NT; ++t) {
        const int bn  = bc ? bc - 1 : 2;       // (t+2) % 3
        const int bcA = bc * (BM * BK), bcB = bc * (BN * BK);
        const int bnA = bn * (BM * BK), bnB = bn * (BN * BK);
        const bool do_stage = (t + 2 < NT);

        // ================= phase 1: N-half 0 =================
        bf16x8 af[4][2], bb[2][2];
#pragma unroll
        for (int i = 0; i < 4; ++i)
#pragma unroll
            for (int h = 0; h < 2; ++h)
                af[i][h] = *(const bf16x8*)&As[bcA + (wm + i * 16 + r) * BK +
                                              (((h * 4 + quad) ^ r7) << 3)];
#pragma unroll
        for (int j = 0; j < 2; ++j)
#pragma unroll
            for (int h = 0; h < 2; ++h)
                bb[j][h] = *(const bf16x8*)&Bs[bcB + (wn + j * 16 + r) * BK +
                                               (((h * 4 + quad) ^ r7) << 3)];
        if (do_stage) {
            gload_lds16(gA_s[0], As + bnA + ldsAo[0]);
            gload_lds16(gA_s[1], As + bnA + ldsAo[1]);
            gload_lds16(gA_s[2], As + bnA + ldsAo[2]);
        }

        asm volatile("" ::: "memory");
        __builtin_amdgcn_s_barrier();
        asm volatile("s_waitcnt lgkmcnt(0)" ::: "memory");
        __builtin_amdgcn_sched_barrier(0);
        __builtin_amdgcn_s_setprio(1);
#pragma unroll
        for (int i = 0; i < 4; ++i)
#pragma unroll
            for (int j = 0; j < 2; ++j) {
                acc[i][j] = __builtin_amdgcn_mfma_f32_16x16x32_bf16(
                    af[i][0], bb[j][0], acc[i][j], 0, 0, 0);
                acc[i][j] = __builtin_amdgcn_mfma_f32_16x16x32_bf16(
                    af[i][1], bb[j][1], acc[i][j], 0, 0, 0);
            }
        __builtin_amdgcn_s_setprio(0);
        asm volatile("" ::: "memory");
        __builtin_amdgcn_s_barrier();
        asm volatile("" ::: "memory");

        // ================= phase 2: N-half 1 =================
        bf16x8 bb2[2][2];
#pragma unroll
        for (int j = 0; j < 2; ++j)
#pragma unroll
            for (int h = 0; h < 2; ++h)
                bb2[j][h] = *(const bf16x8*)&Bs[bcB + (wn + (j + 2) * 16 + r) * BK +
                                                (((h * 4 + quad) ^ r7) << 3)];
        if (do_stage) {
            gload_lds16(gA_s[3], As + bnA + ldsAo[3]);
            gload_lds16(gB_s[0], Bs + bnB + ldsBo[0]);
            gload_lds16(gB_s[1], Bs + bnB + ldsBo[1]);
#pragma unroll
            for (int j = 0; j < 4; ++j) gA_s[j] += BK;
#pragma unroll
            for (int j = 0; j < 2; ++j) gB_s[j] += BK;
        }

        asm volatile("" ::: "memory");
        __builtin_amdgcn_s_barrier();
        asm volatile("s_waitcnt lgkmcnt(0)" ::: "memory");
        __builtin_amdgcn_sched_barrier(0);
        __builtin_amdgcn_s_setprio(1);
#pragma unroll
        for (int i = 0; i < 4; ++i)
#pragma unroll
            for (int j = 0; j < 2; ++j) {
                acc[i][j + 2] = __builtin_amdgcn_mfma_f32_16x16x32_bf16(
                    af[i][0], bb2[j][0], acc[i][j + 2], 0, 0, 0);
                acc[i][j + 2] = __builtin_amdgcn_mfma_f32_16x16x32_bf16(
                    af[i][1], bb2[j][1], acc[i][j + 2], 0, 0, 0);
            }
        __builtin_amdgcn_s_setprio(0);

        // counted drain: keep this tile's 6 prefetch loads in flight,
        // guarantee tile t+1 (older) has landed.  Epilogue: 6 -> 0.
        if (do_stage)        { asm volatile("s_waitcnt vmcnt(6)" ::: "memory"); }
        else if (t + 1 < NT) { asm volatile("s_waitcnt vmcnt(0)" ::: "memory"); }
        __builtin_amdgcn_s_barrier();
        asm volatile("" ::: "memory");

        bc = (bc == 2) ? 0 : bc + 1;
    }

    // epilogue: C/D layout col = lane&15, row = quad*4 + reg
    const int m_base = ty * BM + wm + quad * 4;
    const int n_base = tx * BN + wn + r;
    float bv[4];
#pragma unroll
    for (int j = 0; j < 4; ++j) bv[j] = bias[n_base + j * 16];

    if (FUSE_RELU_BF16) {
        bf16* Cb = (bf16*)Cout;
#pragma unroll
        for (int i = 0; i < 4; ++i) {
#pragma unroll
            for (int p = 0; p < 4; ++p) {
                size_t row = (size_t)(m_base + i * 16 + p) * (size_t)N;
#pragma unroll
                for (int j = 0; j < 4; ++j) {
                    float v = acc[i][j][p] + bv[j];
                    v = v > 0.f ? v : 0.f;
                    Cb[row + n_base + j * 16] = (bf16)v;
                }
            }
        }
    } else {
        float* Cf = (float*)Cout;
#pragma unroll
        for (int i = 0; i < 4; ++i) {
#pragma unroll
            for (int p = 0; p < 4; ++p) {
                size_t row = (size_t)(m_base + i * 16 + p) * (size_t)N;
#pragma unroll
                for (int j = 0; j < 4; ++j) {
                    Cf[row + n_base + j * 16] = acc[i][j][p] + bv[j];
                }
            }
        }
    }
}

// ---------------------------------------------------------------------------
extern "C" void kernel_launch(void* const* d_in, const int* in_sizes, int n_in,
                              void* d_out, int out_size, void* d_ws, size_t ws_size,
                              hipStream_t stream)
{
    const float* x  = (const float*)d_in[0];  // [8192,1024]
    const float* w1 = (const float*)d_in[1];  // [1024,4096]
    const float* b1 = (const float*)d_in[2];  // [4096]
    const float* w2 = (const float*)d_in[3];  // [4096,1024]
    const float* b2 = (const float*)d_in[4];  // [1024]
    float* out = (float*)d_out;               // [8192,1024]

    const int M = 8192, D = 1024, W = 4096;

    char* ws = (char*)d_ws;
    bf16* xb  = (bf16*)(ws);                           // 16 MiB: [8192,1024]
    bf16* w1t = (bf16*)(ws + (size_t)(16 << 20));      //  8 MiB: [4096,1024]
    bf16* w2t = (bf16*)(ws + (size_t)(24 << 20));      //  8 MiB: [1024,4096]
    bf16* h   = (bf16*)(ws + (size_t)(32 << 20));      // 64 MiB: [8192,4096]

    // 1. cast x -> bf16
    {
        int n4 = (M * D) / 4;
        cast_f32_bf16<<<(n4 + 255) / 256, 256, 0, stream>>>(
            (const float4*)x, (bf16x4*)xb, n4);
    }
    // 2. w1 [D][W] -> w1t [W][D]
    transpose_cast<<<dim3(W / 64, D / 64), 256, 0, stream>>>(w1, w1t, D, W);
    // 3. w2 [W][D] -> w2t [D][W]
    transpose_cast<<<dim3(D / 64, W / 64), 256, 0, stream>>>(w2, w2t, W, D);

    // 4. h = relu(xb @ w1 + b1), bf16  [M][W]   grid 32x32 = 1024 wgs
    {
        int ny = M / BM, nwg = (W / BN) * ny;
        gemm_bt<1><<<nwg, 512, 0, stream>>>(xb, w1t, b1, (void*)h, M, W, D, ny);
    }
    // 5. out = h @ w2 + b2, f32  [M][D]         grid 8x32 = 256 wgs (1/CU)
    {
        int ny = M / BM, nwg = (D / BN) * ny;
        gemm_bt<0><<<nwg, 512, 0, stream>>>(h, w2t, b2, (void*)out, M, D, W, ny);
    }
}

// Round 4
// 274.130 us; speedup vs baseline: 1.0931x; 1.0931x over previous
//
#include <hip/hip_runtime.h>
#include <hip/hip_bf16.h>

// Dense FFN: out = relu(x @ w1 + b1) @ w2 + b2
// x  [8192,1024] f32, w1 [1024,4096] f32, b1 [4096] f32,
// w2 [4096,1024] f32, b2 [1024] f32, out [8192,1024] f32.
//
// R4: revert to the verified R2 GEMM structure (128x128, BK=64, 256 thr,
// measured 84.5 us/GEMM, 0 bank conflicts) -- R3's 1-block/CU lockstep
// pipeline regressed (107 us, MfmaUtil 25%). Single new variable vs R2:
// T1 XCD-bijective block remap (1D grid, N-major panels) so each XCD keeps
// one B-panel (256 KB) L2-resident and neighbor blocks share A rows.
// nwg: GEMM1 = 2048, GEMM2 = 512; both % 8 == 0 (bijective simple form).

typedef __bf16 bf16;
typedef __bf16 bf16x4 __attribute__((ext_vector_type(4)));
typedef __bf16 bf16x8 __attribute__((ext_vector_type(8)));
typedef float  f32x4  __attribute__((ext_vector_type(4)));

#define BM 128
#define BN 128
#define BK 64

__device__ __forceinline__ void gload_lds16(const bf16* g, bf16* l) {
    __builtin_amdgcn_global_load_lds(
        (const __attribute__((address_space(1))) unsigned int*)g,
        (__attribute__((address_space(3))) unsigned int*)l,
        16, 0, 0);
}

// ---------------------------------------------------------------------------
// cast f32 -> bf16, 4 elems/thread
__global__ __launch_bounds__(256) void cast_f32_bf16(
    const float4* __restrict__ in, bf16x4* __restrict__ out, int n4)
{
    int i = blockIdx.x * 256 + threadIdx.x;
    if (i < n4) {
        float4 v = in[i];
        bf16x4 o;
        o.x = (bf16)v.x; o.y = (bf16)v.y; o.z = (bf16)v.z; o.w = (bf16)v.w;
        out[i] = o;
    }
}

// ---------------------------------------------------------------------------
// transpose + cast: in [K][N] f32  ->  out [N][K] bf16.  64x64 tiles.
__global__ __launch_bounds__(256) void transpose_cast(
    const float* __restrict__ in, bf16* __restrict__ out, int K, int N)
{
    __shared__ __align__(16) bf16 tile[64][72];   // [n][k], pad to 72
    const int k0 = blockIdx.y * 64;
    const int n0 = blockIdx.x * 64;
    const int t  = threadIdx.x;

    const int lr = t >> 4;          // 0..15
    const int lc = (t & 15) << 2;   // 0,4,..60
#pragma unroll
    for (int p = 0; p < 4; ++p) {
        int k = p * 16 + lr;
        float4 v = *(const float4*)(in + (size_t)(k0 + k) * N + n0 + lc);
        tile[lc + 0][k] = (bf16)v.x;
        tile[lc + 1][k] = (bf16)v.y;
        tile[lc + 2][k] = (bf16)v.z;
        tile[lc + 3][k] = (bf16)v.w;
    }
    __syncthreads();

    const int wr = t >> 3;          // 0..31
    const int wc = (t & 7) << 3;    // 0,8,..56
#pragma unroll
    for (int p = 0; p < 2; ++p) {
        int n = p * 32 + wr;
        *(bf16x8*)(out + (size_t)(n0 + n) * K + k0 + wc) =
            *(const bf16x8*)&tile[n][wc];
    }
}

// ---------------------------------------------------------------------------
// C[m][n] = sum_k A[m][k] * Bt[n][k]  (+bias, opt relu)
// A [M][K] bf16, Bt [N][K] bf16.  Block = 256 thr = 4 waves, tile 128x128,
// BK=64.  Wave w -> 64x64 subtile (w>>1, w&1).  16x16x32 bf16 MFMA.
// LDS layout: row r (64 elems = 8 chunks of 16B); chunk slot c holds global
// chunk (c ^ (r&7)).  Staging permutes the global source per lane; fragment
// reads XOR the chunk index, landing at the bank floor (measured 0 conflicts).
// Grid: 1D, XCD-bijective remap, N-major tile order (ty fastest).
template <int FUSE_RELU_BF16>
__global__ __launch_bounds__(256, 3) void gemm_bt(
    const bf16* __restrict__ A, const bf16* __restrict__ Bt,
    const float* __restrict__ bias, void* __restrict__ Cout,
    int M, int N, int K, int ny)
{
    __shared__ __align__(16) bf16 As[BM * BK];
    __shared__ __align__(16) bf16 Bs[BN * BK];

    // T1: XCD-bijective remap (nwg % 8 == 0 for our shapes).
    const int nwg = gridDim.x;
    const int bid = blockIdx.x;
    const int L   = (bid & 7) * (nwg >> 3) + (bid >> 3);
    const int tx  = L / ny;          // N-block (panel)
    const int ty  = L - tx * ny;     // M-block (fast within panel)

    const int tid  = threadIdx.x;
    const int wave = tid >> 6;
    const int lane = tid & 63;

    // staging: each gload covers 8 rows x 64 elems (8 lanes/row, 16B/lane)
    const int l8  = lane >> 3;           // row within 8-row group
    const int c8  = lane & 7;            // LDS chunk slot
    const int swc = (c8 ^ l8) << 3;      // swizzled global chunk -> elem offset
    const size_t K_ = (size_t)K;

    const bf16* gA[4]; const bf16* gB[4];
    bf16* lA[4]; bf16* lB[4];
#pragma unroll
    for (int g = 0; g < 4; ++g) {
        const int rr = wave * 32 + g * 8 + l8;
        gA[g] = A  + ((size_t)ty * BM + rr) * K_ + swc;
        gB[g] = Bt + ((size_t)tx * BN + rr) * K_ + swc;
        lA[g] = &As[(wave * 32 + g * 8) * BK] + lane * 8;
        lB[g] = &Bs[(wave * 32 + g * 8) * BK] + lane * 8;
    }

    const int wm   = (wave >> 1) << 6;
    const int wn   = (wave & 1) << 6;
    const int quad = lane >> 4;
    const int r    = lane & 15;
    const int r7   = lane & 7;

    f32x4 acc[4][4] = {};

    for (int k0 = 0; k0 < K; k0 += BK) {
        __syncthreads();
#pragma unroll
        for (int g = 0; g < 4; ++g) {
            gload_lds16(gA[g], lA[g]);
            gload_lds16(gB[g], lB[g]);
            gA[g] += BK; gB[g] += BK;
        }
        __syncthreads();

#pragma unroll
        for (int h = 0; h < 2; ++h) {
            const int ch = ((h * 4 + quad) ^ r7) << 3;   // swizzled chunk offset
            bf16x8 af[4], bfr[4];
#pragma unroll
            for (int i = 0; i < 4; ++i)
                af[i] = *(const bf16x8*)&As[(wm + i * 16 + r) * BK + ch];
#pragma unroll
            for (int j = 0; j < 4; ++j)
                bfr[j] = *(const bf16x8*)&Bs[(wn + j * 16 + r) * BK + ch];
#pragma unroll
            for (int i = 0; i < 4; ++i)
#pragma unroll
                for (int j = 0; j < 4; ++j)
                    acc[i][j] = __builtin_amdgcn_mfma_f32_16x16x32_bf16(
                        af[i], bfr[j], acc[i][j], 0, 0, 0);
        }
    }

    // epilogue: C/D layout col = lane&15, row = quad*4 + reg
    const int m_base = ty * BM + wm + quad * 4;
    const int n_base = tx * BN + wn + r;
    float bv[4];
#pragma unroll
    for (int j = 0; j < 4; ++j) bv[j] = bias[n_base + j * 16];

    if (FUSE_RELU_BF16) {
        bf16* Cb = (bf16*)Cout;
#pragma unroll
        for (int i = 0; i < 4; ++i) {
#pragma unroll
            for (int p = 0; p < 4; ++p) {
                size_t row = (size_t)(m_base + i * 16 + p) * (size_t)N;
#pragma unroll
                for (int j = 0; j < 4; ++j) {
                    float v = acc[i][j][p] + bv[j];
                    v = v > 0.f ? v : 0.f;
                    Cb[row + n_base + j * 16] = (bf16)v;
                }
            }
        }
    } else {
        float* Cf = (float*)Cout;
#pragma unroll
        for (int i = 0; i < 4; ++i) {
#pragma unroll
            for (int p = 0; p < 4; ++p) {
                size_t row = (size_t)(m_base + i * 16 + p) * (size_t)N;
#pragma unroll
                for (int j = 0; j < 4; ++j) {
                    Cf[row + n_base + j * 16] = acc[i][j][p] + bv[j];
                }
            }
        }
    }
}

// ---------------------------------------------------------------------------
extern "C" void kernel_launch(void* const* d_in, const int* in_sizes, int n_in,
                              void* d_out, int out_size, void* d_ws, size_t ws_size,
                              hipStream_t stream)
{
    const float* x  = (const float*)d_in[0];  // [8192,1024]
    const float* w1 = (const float*)d_in[1];  // [1024,4096]
    const float* b1 = (const float*)d_in[2];  // [4096]
    const float* w2 = (const float*)d_in[3];  // [4096,1024]
    const float* b2 = (const float*)d_in[4];  // [1024]
    float* out = (float*)d_out;               // [8192,1024]

    const int M = 8192, D = 1024, W = 4096;

    char* ws = (char*)d_ws;
    bf16* xb  = (bf16*)(ws);                           // 16 MiB: [8192,1024]
    bf16* w1t = (bf16*)(ws + (size_t)(16 << 20));      //  8 MiB: [4096,1024]
    bf16* w2t = (bf16*)(ws + (size_t)(24 << 20));      //  8 MiB: [1024,4096]
    bf16* h   = (bf16*)(ws + (size_t)(32 << 20));      // 64 MiB: [8192,4096]

    // 1. cast x -> bf16
    {
        int n4 = (M * D) / 4;
        cast_f32_bf16<<<(n4 + 255) / 256, 256, 0, stream>>>(
            (const float4*)x, (bf16x4*)xb, n4);
    }
    // 2. w1 [D][W] -> w1t [W][D]
    transpose_cast<<<dim3(W / 64, D / 64), 256, 0, stream>>>(w1, w1t, D, W);
    // 3. w2 [W][D] -> w2t [D][W]
    transpose_cast<<<dim3(D / 64, W / 64), 256, 0, stream>>>(w2, w2t, W, D);

    // 4. h = relu(xb @ w1 + b1), bf16  [M][W]   grid 32*64 = 2048 wgs
    {
        int ny = M / BM, nwg = (W / BN) * ny;
        gemm_bt<1><<<nwg, 256, 0, stream>>>(xb, w1t, b1, (void*)h, M, W, D, ny);
    }
    // 5. out = h @ w2 + b2, f32  [M][D]         grid 8*64 = 512 wgs
    {
        int ny = M / BM, nwg = (D / BN) * ny;
        gemm_bt<0><<<nwg, 256, 0, stream>>>(h, w2t, b2, (void*)out, M, D, W, ny);
    }
}

// Round 5
// 263.145 us; speedup vs baseline: 1.1387x; 1.0417x over previous
//
#include <hip/hip_runtime.h>
#include <hip/hip_bf16.h>

// Dense FFN: out = relu(x @ w1 + b1) @ w2 + b2
// x  [8192,1024] f32, w1 [1024,4096] f32, b1 [4096] f32,
// w2 [4096,1024] f32, b2 [1024] f32, out [8192,1024] f32.
//
// R5: (A) revert grid to R0 default 2D (R4's XCD remap hurt GEMM1: 84->90us);
//     (B) MFMA 16x16x32 -> 32x32x16 (m119: 129 vs 155 matrix-pipe cyc per
//         wave-K-step, half the MFMA instr count; same LDS traffic & swizzle);
//     (C) fuse cast + 2 transposes into one prep kernel (launch overhead).
// The 2-barrier K-loop, staging, and chunk-XOR swizzle are byte-identical to
// the verified R2 kernel (0 bank conflicts measured).

typedef __bf16 bf16;
typedef __bf16 bf16x4 __attribute__((ext_vector_type(4)));
typedef __bf16 bf16x8 __attribute__((ext_vector_type(8)));
typedef float  f32x16 __attribute__((ext_vector_type(16)));

#define BM 128
#define BN 128
#define BK 64

__device__ __forceinline__ void gload_lds16(const bf16* g, bf16* l) {
    __builtin_amdgcn_global_load_lds(
        (const __attribute__((address_space(1))) unsigned int*)g,
        (__attribute__((address_space(3))) unsigned int*)l,
        16, 0, 0);
}

// ---------------------------------------------------------------------------
// fused prep: [0,8192) cast x->bf16; [8192,9216) w1 transpose;
//             [9216,10240) w2 transpose.  All block-uniform branches.
__device__ __forceinline__ void transpose_tile(
    const float* __restrict__ in, bf16* __restrict__ out,
    int K, int N, int k0, int n0, int t, bf16 (*tile)[72])
{
    const int lr = t >> 4;          // 0..15
    const int lc = (t & 15) << 2;   // 0,4,..60
#pragma unroll
    for (int p = 0; p < 4; ++p) {
        int k = p * 16 + lr;
        float4 v = *(const float4*)(in + (size_t)(k0 + k) * N + n0 + lc);
        tile[lc + 0][k] = (bf16)v.x;
        tile[lc + 1][k] = (bf16)v.y;
        tile[lc + 2][k] = (bf16)v.z;
        tile[lc + 3][k] = (bf16)v.w;
    }
    __syncthreads();

    const int wr = t >> 3;          // 0..31
    const int wc = (t & 7) << 3;    // 0,8,..56
#pragma unroll
    for (int p = 0; p < 2; ++p) {
        int n = p * 32 + wr;
        *(bf16x8*)(out + (size_t)(n0 + n) * K + k0 + wc) =
            *(const bf16x8*)&tile[n][wc];
    }
}

__global__ __launch_bounds__(256) void prep_fused(
    const float* __restrict__ x,  bf16* __restrict__ xb,
    const float* __restrict__ w1, bf16* __restrict__ w1t,
    const float* __restrict__ w2, bf16* __restrict__ w2t)
{
    __shared__ __align__(16) bf16 tile[64][72];
    const int bid = blockIdx.x;
    const int t   = threadIdx.x;

    if (bid < 8192) {
        // cast x -> bf16, 4 f32/thread, exactly 8192*256 threads for 8M elems
        int i = bid * 256 + t;
        float4 v = ((const float4*)x)[i];
        bf16x4 o;
        o.x = (bf16)v.x; o.y = (bf16)v.y; o.z = (bf16)v.z; o.w = (bf16)v.w;
        ((bf16x4*)xb)[i] = o;
    } else if (bid < 9216) {
        // w1 [1024][4096] -> w1t [4096][1024]; grid was (64 x, 16 y)
        int b = bid - 8192;
        transpose_tile(w1, w1t, 1024, 4096, (b >> 6) * 64, (b & 63) * 64, t, tile);
    } else {
        // w2 [4096][1024] -> w2t [1024][4096]; grid was (16 x, 64 y)
        int b = bid - 9216;
        transpose_tile(w2, w2t, 4096, 1024, (b >> 4) * 64, (b & 15) * 64, t, tile);
    }
}

// ---------------------------------------------------------------------------
// C[m][n] = sum_k A[m][k] * Bt[n][k]  (+bias, opt relu)
// A [M][K] bf16, Bt [N][K] bf16.  Block = 256 thr = 4 waves, tile 128x128,
// BK=64.  Wave w -> 64x64 subtile (w>>1, w&1), computed as 2x2 of 32x32
// MFMA tiles (v_mfma_f32_32x32x16_bf16, 16 ops/K-step/wave).
// LDS layout: row r (64 elems = 8 chunks of 16B); chunk slot c holds global
// chunk (c ^ (r&7)).  Staging permutes the global source per lane; fragment
// reads XOR the chunk index (conflict-free, measured 0 in R2).
// A/B fragment (32x32x16): lane l holds row/col (l&31), k = (l>>5)*8 + e,
// k-chunk for sub-step c = 2c + (l>>5).
// C/D layout (m74/m101): col = lane&31, row = (reg&3) + 8*(reg>>2) + 4*(l>>5).
template <int FUSE_RELU_BF16>
__global__ __launch_bounds__(256, 3) void gemm_bt(
    const bf16* __restrict__ A, const bf16* __restrict__ Bt,
    const float* __restrict__ bias, void* __restrict__ Cout,
    int M, int N, int K)
{
    __shared__ __align__(16) bf16 As[BM * BK];
    __shared__ __align__(16) bf16 Bs[BN * BK];

    const int tx = blockIdx.x;       // N-block
    const int ty = blockIdx.y;       // M-block

    const int tid  = threadIdx.x;
    const int wave = tid >> 6;
    const int lane = tid & 63;

    // staging: each gload covers 8 rows x 64 elems (8 lanes/row, 16B/lane)
    const int l8  = lane >> 3;           // row within 8-row group
    const int c8  = lane & 7;            // LDS chunk slot
    const int swc = (c8 ^ l8) << 3;      // swizzled global chunk -> elem offset
    const size_t K_ = (size_t)K;

    const bf16* gA[4]; const bf16* gB[4];
    bf16* lA[4]; bf16* lB[4];
#pragma unroll
    for (int g = 0; g < 4; ++g) {
        const int rr = wave * 32 + g * 8 + l8;
        gA[g] = A  + ((size_t)ty * BM + rr) * K_ + swc;
        gB[g] = Bt + ((size_t)tx * BN + rr) * K_ + swc;
        lA[g] = &As[(wave * 32 + g * 8) * BK] + lane * 8;
        lB[g] = &Bs[(wave * 32 + g * 8) * BK] + lane * 8;
    }

    const int wm  = (wave >> 1) << 6;    // 0,64
    const int wn  = (wave & 1) << 6;     // 0,64
    const int c31 = lane & 31;           // row/col within 32x32 tile
    const int kh  = lane >> 5;           // k-half select
    const int r7  = lane & 7;

    f32x16 acc[2][2] = {};

    for (int k0 = 0; k0 < K; k0 += BK) {
        __syncthreads();
#pragma unroll
        for (int g = 0; g < 4; ++g) {
            gload_lds16(gA[g], lA[g]);
            gload_lds16(gB[g], lB[g]);
            gA[g] += BK; gB[g] += BK;
        }
        __syncthreads();

#pragma unroll
        for (int c = 0; c < 4; ++c) {                 // k-sub-step of 16
            const int ch = ((2 * c + kh) ^ r7) << 3;  // swizzled chunk offset
            bf16x8 a0 = *(const bf16x8*)&As[(wm +      c31) * BK + ch];
            bf16x8 a1 = *(const bf16x8*)&As[(wm + 32 + c31) * BK + ch];
            bf16x8 b0 = *(const bf16x8*)&Bs[(wn +      c31) * BK + ch];
            bf16x8 b1 = *(const bf16x8*)&Bs[(wn + 32 + c31) * BK + ch];
            acc[0][0] = __builtin_amdgcn_mfma_f32_32x32x16_bf16(a0, b0, acc[0][0], 0, 0, 0);
            acc[0][1] = __builtin_amdgcn_mfma_f32_32x32x16_bf16(a0, b1, acc[0][1], 0, 0, 0);
            acc[1][0] = __builtin_amdgcn_mfma_f32_32x32x16_bf16(a1, b0, acc[1][0], 0, 0, 0);
            acc[1][1] = __builtin_amdgcn_mfma_f32_32x32x16_bf16(a1, b1, acc[1][1], 0, 0, 0);
        }
    }

    // epilogue: C/D col = lane&31, row = (reg&3) + 8*(reg>>2) + 4*kh
    const int m_base = ty * BM + wm + 4 * kh;
    const int n_base = tx * BN + wn + c31;
    float bv[2];
#pragma unroll
    for (int j = 0; j < 2; ++j) bv[j] = bias[n_base + j * 32];

    if (FUSE_RELU_BF16) {
        bf16* Cb = (bf16*)Cout;
#pragma unroll
        for (int i = 0; i < 2; ++i) {
#pragma unroll
            for (int reg = 0; reg < 16; ++reg) {
                size_t row = (size_t)(m_base + i * 32 + (reg & 3) + 8 * (reg >> 2)) * (size_t)N;
#pragma unroll
                for (int j = 0; j < 2; ++j) {
                    float v = acc[i][j][reg] + bv[j];
                    v = v > 0.f ? v : 0.f;
                    Cb[row + n_base + j * 32] = (bf16)v;
                }
            }
        }
    } else {
        float* Cf = (float*)Cout;
#pragma unroll
        for (int i = 0; i < 2; ++i) {
#pragma unroll
            for (int reg = 0; reg < 16; ++reg) {
                size_t row = (size_t)(m_base + i * 32 + (reg & 3) + 8 * (reg >> 2)) * (size_t)N;
#pragma unroll
                for (int j = 0; j < 2; ++j) {
                    Cf[row + n_base + j * 32] = acc[i][j][reg] + bv[j];
                }
            }
        }
    }
}

// ---------------------------------------------------------------------------
extern "C" void kernel_launch(void* const* d_in, const int* in_sizes, int n_in,
                              void* d_out, int out_size, void* d_ws, size_t ws_size,
                              hipStream_t stream)
{
    const float* x  = (const float*)d_in[0];  // [8192,1024]
    const float* w1 = (const float*)d_in[1];  // [1024,4096]
    const float* b1 = (const float*)d_in[2];  // [4096]
    const float* w2 = (const float*)d_in[3];  // [4096,1024]
    const float* b2 = (const float*)d_in[4];  // [1024]
    float* out = (float*)d_out;               // [8192,1024]

    const int M = 8192, D = 1024, W = 4096;

    char* ws = (char*)d_ws;
    bf16* xb  = (bf16*)(ws);                           // 16 MiB: [8192,1024]
    bf16* w1t = (bf16*)(ws + (size_t)(16 << 20));      //  8 MiB: [4096,1024]
    bf16* w2t = (bf16*)(ws + (size_t)(24 << 20));      //  8 MiB: [1024,4096]
    bf16* h   = (bf16*)(ws + (size_t)(32 << 20));      // 64 MiB: [8192,4096]

    // 1. fused prep: cast x + transpose w1 + transpose w2 (one launch)
    prep_fused<<<10240, 256, 0, stream>>>(x, xb, w1, w1t, w2, w2t);

    // 2. h = relu(xb @ w1 + b1), bf16  [M][W]
    gemm_bt<1><<<dim3(W / BN, M / BM), 256, 0, stream>>>(
        xb, w1t, b1, (void*)h, M, W, D);

    // 3. out = h @ w2 + b2, f32  [M][D]
    gemm_bt<0><<<dim3(D / BN, M / BM), 256, 0, stream>>>(
        h, w2t, b2, (void*)out, M, D, W);
}

// Round 6
// 247.702 us; speedup vs baseline: 1.2097x; 1.0623x over previous
//
#include <hip/hip_runtime.h>
#include <hip/hip_bf16.h>

// Dense FFN: out = relu(x @ w1 + b1) @ w2 + b2
// x  [8192,1024] f32, w1 [1024,4096] f32, b1 [4096] f32,
// w2 [4096,1024] f32, b2 [1024] f32, out [8192,1024] f32.
//
// R6 = verified-best recombination:
//   GEMM: byte-exact R2 body (128x128, BK=64, 256 thr, 16x16x32 MFMA,
//         chunk-XOR swizzle, default 2D grid) -- measured 84.6 us, 0 bank
//         conflicts, three separate sessions. R5's 32x32 variant produced
//         8.4M conflicts/dispatch (+13 us/GEMM) -> reverted.
//   Prep: single fused kernel (cast x + transpose w1 + transpose w2) --
//         measured -17 us vs 3 separate launches in R5, passed.

typedef __bf16 bf16;
typedef __bf16 bf16x4 __attribute__((ext_vector_type(4)));
typedef __bf16 bf16x8 __attribute__((ext_vector_type(8)));
typedef float  f32x4  __attribute__((ext_vector_type(4)));

#define BM 128
#define BN 128
#define BK 64

__device__ __forceinline__ void gload_lds16(const bf16* g, bf16* l) {
    __builtin_amdgcn_global_load_lds(
        (const __attribute__((address_space(1))) unsigned int*)g,
        (__attribute__((address_space(3))) unsigned int*)l,
        16, 0, 0);
}

// ---------------------------------------------------------------------------
// fused prep: [0,8192) cast x->bf16; [8192,9216) w1 transpose;
//             [9216,10240) w2 transpose.  All block-uniform branches.
__device__ __forceinline__ void transpose_tile(
    const float* __restrict__ in, bf16* __restrict__ out,
    int K, int N, int k0, int n0, int t, bf16 (*tile)[72])
{
    const int lr = t >> 4;          // 0..15
    const int lc = (t & 15) << 2;   // 0,4,..60
#pragma unroll
    for (int p = 0; p < 4; ++p) {
        int k = p * 16 + lr;
        float4 v = *(const float4*)(in + (size_t)(k0 + k) * N + n0 + lc);
        tile[lc + 0][k] = (bf16)v.x;
        tile[lc + 1][k] = (bf16)v.y;
        tile[lc + 2][k] = (bf16)v.z;
        tile[lc + 3][k] = (bf16)v.w;
    }
    __syncthreads();

    const int wr = t >> 3;          // 0..31
    const int wc = (t & 7) << 3;    // 0,8,..56
#pragma unroll
    for (int p = 0; p < 2; ++p) {
        int n = p * 32 + wr;
        *(bf16x8*)(out + (size_t)(n0 + n) * K + k0 + wc) =
            *(const bf16x8*)&tile[n][wc];
    }
}

__global__ __launch_bounds__(256) void prep_fused(
    const float* __restrict__ x,  bf16* __restrict__ xb,
    const float* __restrict__ w1, bf16* __restrict__ w1t,
    const float* __restrict__ w2, bf16* __restrict__ w2t)
{
    __shared__ __align__(16) bf16 tile[64][72];
    const int bid = blockIdx.x;
    const int t   = threadIdx.x;

    if (bid < 8192) {
        // cast x -> bf16, 4 f32/thread, exactly 8192*256 threads for 8M elems
        int i = bid * 256 + t;
        float4 v = ((const float4*)x)[i];
        bf16x4 o;
        o.x = (bf16)v.x; o.y = (bf16)v.y; o.z = (bf16)v.z; o.w = (bf16)v.w;
        ((bf16x4*)xb)[i] = o;
    } else if (bid < 9216) {
        // w1 [1024][4096] -> w1t [4096][1024]
        int b = bid - 8192;
        transpose_tile(w1, w1t, 1024, 4096, (b >> 6) * 64, (b & 63) * 64, t, tile);
    } else {
        // w2 [4096][1024] -> w2t [1024][4096]
        int b = bid - 9216;
        transpose_tile(w2, w2t, 4096, 1024, (b >> 4) * 64, (b & 15) * 64, t, tile);
    }
}

// ---------------------------------------------------------------------------
// C[m][n] = sum_k A[m][k] * Bt[n][k]  (+bias, opt relu)
// A [M][K] bf16, Bt [N][K] bf16.  Block = 256 thr = 4 waves, tile 128x128,
// BK=64.  Wave w -> 64x64 subtile (w>>1, w&1).  16x16x32 bf16 MFMA.
// LDS layout: row r (64 elems = 8 chunks of 16B); chunk slot c holds global
// chunk (c ^ (r&7)).  Staging permutes the global source per lane; fragment
// reads XOR the chunk index, landing at the bank floor (measured 0 conflicts).
template <int FUSE_RELU_BF16>
__global__ __launch_bounds__(256, 3) void gemm_bt(
    const bf16* __restrict__ A, const bf16* __restrict__ Bt,
    const float* __restrict__ bias, void* __restrict__ Cout,
    int M, int N, int K)
{
    __shared__ __align__(16) bf16 As[BM * BK];
    __shared__ __align__(16) bf16 Bs[BN * BK];

    const int tid  = threadIdx.x;
    const int wave = tid >> 6;
    const int lane = tid & 63;

    // staging: each gload covers 8 rows x 64 elems (8 lanes/row, 16B/lane)
    const int l8  = lane >> 3;           // row within 8-row group
    const int c8  = lane & 7;            // LDS chunk slot
    const int swc = (c8 ^ l8) << 3;      // swizzled global chunk -> elem offset
    const size_t K_ = (size_t)K;

    const bf16* gA[4]; const bf16* gB[4];
    bf16* lA[4]; bf16* lB[4];
#pragma unroll
    for (int g = 0; g < 4; ++g) {
        const int rr = wave * 32 + g * 8 + l8;
        gA[g] = A  + ((size_t)blockIdx.y * BM + rr) * K_ + swc;
        gB[g] = Bt + ((size_t)blockIdx.x * BN + rr) * K_ + swc;
        lA[g] = &As[(wave * 32 + g * 8) * BK] + lane * 8;
        lB[g] = &Bs[(wave * 32 + g * 8) * BK] + lane * 8;
    }

    const int wm   = (wave >> 1) << 6;
    const int wn   = (wave & 1) << 6;
    const int quad = lane >> 4;
    const int r    = lane & 15;
    const int r7   = lane & 7;

    f32x4 acc[4][4] = {};

    for (int k0 = 0; k0 < K; k0 += BK) {
        __syncthreads();
#pragma unroll
        for (int g = 0; g < 4; ++g) {
            gload_lds16(gA[g], lA[g]);
            gload_lds16(gB[g], lB[g]);
            gA[g] += BK; gB[g] += BK;
        }
        __syncthreads();

#pragma unroll
        for (int h = 0; h < 2; ++h) {
            const int ch = ((h * 4 + quad) ^ r7) << 3;   // swizzled chunk offset
            bf16x8 af[4], bfr[4];
#pragma unroll
            for (int i = 0; i < 4; ++i)
                af[i] = *(const bf16x8*)&As[(wm + i * 16 + r) * BK + ch];
#pragma unroll
            for (int j = 0; j < 4; ++j)
                bfr[j] = *(const bf16x8*)&Bs[(wn + j * 16 + r) * BK + ch];
#pragma unroll
            for (int i = 0; i < 4; ++i)
#pragma unroll
                for (int j = 0; j < 4; ++j)
                    acc[i][j] = __builtin_amdgcn_mfma_f32_16x16x32_bf16(
                        af[i], bfr[j], acc[i][j], 0, 0, 0);
        }
    }

    // epilogue: C/D layout col = lane&15, row = quad*4 + reg
    const int m_base = blockIdx.y * BM + wm + quad * 4;
    const int n_base = blockIdx.x * BN + wn + r;
    float bv[4];
#pragma unroll
    for (int j = 0; j < 4; ++j) bv[j] = bias[n_base + j * 16];

    if (FUSE_RELU_BF16) {
        bf16* Cb = (bf16*)Cout;
#pragma unroll
        for (int i = 0; i < 4; ++i) {
#pragma unroll
            for (int p = 0; p < 4; ++p) {
                size_t row = (size_t)(m_base + i * 16 + p) * (size_t)N;
#pragma unroll
                for (int j = 0; j < 4; ++j) {
                    float v = acc[i][j][p] + bv[j];
                    v = v > 0.f ? v : 0.f;
                    Cb[row + n_base + j * 16] = (bf16)v;
                }
            }
        }
    } else {
        float* Cf = (float*)Cout;
#pragma unroll
        for (int i = 0; i < 4; ++i) {
#pragma unroll
            for (int p = 0; p < 4; ++p) {
                size_t row = (size_t)(m_base + i * 16 + p) * (size_t)N;
#pragma unroll
                for (int j = 0; j < 4; ++j) {
                    Cf[row + n_base + j * 16] = acc[i][j][p] + bv[j];
                }
            }
        }
    }
}

// ---------------------------------------------------------------------------
extern "C" void kernel_launch(void* const* d_in, const int* in_sizes, int n_in,
                              void* d_out, int out_size, void* d_ws, size_t ws_size,
                              hipStream_t stream)
{
    const float* x  = (const float*)d_in[0];  // [8192,1024]
    const float* w1 = (const float*)d_in[1];  // [1024,4096]
    const float* b1 = (const float*)d_in[2];  // [4096]
    const float* w2 = (const float*)d_in[3];  // [4096,1024]
    const float* b2 = (const float*)d_in[4];  // [1024]
    float* out = (float*)d_out;               // [8192,1024]

    const int M = 8192, D = 1024, W = 4096;

    char* ws = (char*)d_ws;
    bf16* xb  = (bf16*)(ws);                           // 16 MiB: [8192,1024]
    bf16* w1t = (bf16*)(ws + (size_t)(16 << 20));      //  8 MiB: [4096,1024]
    bf16* w2t = (bf16*)(ws + (size_t)(24 << 20));      //  8 MiB: [1024,4096]
    bf16* h   = (bf16*)(ws + (size_t)(32 << 20));      // 64 MiB: [8192,4096]

    // 1. fused prep: cast x + transpose w1 + transpose w2 (one launch)
    prep_fused<<<10240, 256, 0, stream>>>(x, xb, w1, w1t, w2, w2t);

    // 2. h = relu(xb @ w1 + b1), bf16  [M][W]
    gemm_bt<1><<<dim3(W / BN, M / BM), 256, 0, stream>>>(
        xb, w1t, b1, (void*)h, M, W, D);

    // 3. out = h @ w2 + b2, f32  [M][D]
    gemm_bt<0><<<dim3(D / BN, M / BM), 256, 0, stream>>>(
        h, w2t, b2, (void*)out, M, D, W);
}